// Round 3
// baseline (307.626 us; speedup 1.0000x reference)
//
#include <hip/hip_runtime.h>
#include <hip/hip_bf16.h>
#include <math.h>

#define D_MODEL 1024
#define NHEAD   16
#define HEAD_DIM 64
#define BATCH   4
#define SEQ     2048

typedef __attribute__((ext_vector_type(8))) short bf16x8;
typedef __attribute__((ext_vector_type(4))) float f32x4;
typedef __attribute__((ext_vector_type(16))) float f32x16;

__device__ inline ushort f2bf(float f) {
  __hip_bfloat16 h = __float2bfloat16(f);
  return *reinterpret_cast<ushort*>(&h);
}
__device__ inline uint pk2(float a, float b) {
  return (uint)f2bf(a) | ((uint)f2bf(b) << 16);
}
__device__ inline float bf2f(ushort u) {
  return __uint_as_float((uint)u << 16);
}
__device__ inline f32x16 zero16() {
  f32x16 z;
#pragma unroll
  for (int i = 0; i < 16; ++i) z[i] = 0.f;
  return z;
}
// async 16B global -> LDS (dest = wave-uniform base + lane*16; LDS must be unpadded)
__device__ inline void gld_lds16(const ushort* g, ushort* l) {
  __builtin_amdgcn_global_load_lds(
      (const __attribute__((address_space(1))) void*)g,
      (__attribute__((address_space(3))) void*)l, 16, 0, 0);
}

// ---------------- diagnostic fill ----------------
__global__ __launch_bounds__(256) void fill_f32(float* __restrict__ p, int n, float v) {
  int i = blockIdx.x * 256 + threadIdx.x;
  if (i < n) p[i] = v;
}

// ---------------- x: fp32 -> bf16 (8 elems/thread) ----------------
__global__ __launch_bounds__(256) void cast_bf16(const float* __restrict__ in,
                                                 ushort* __restrict__ out, int n8) {
  int i = blockIdx.x * 256 + threadIdx.x;
  if (i >= n8) return;
  const float4* p = (const float4*)(in + i * 8);
  float4 a = p[0], b = p[1];
  uint4 o;
  o.x = pk2(a.x, a.y); o.y = pk2(a.z, a.w);
  o.z = pk2(b.x, b.y); o.w = pk2(b.z, b.w);
  ((uint4*)out)[i] = o;
}

// ---------------- fp32 -> bf16 transpose: in[R][C] f32 -> out[C][R] bf16 ----------------
__global__ __launch_bounds__(256) void transpose_f32_bf16(const float* __restrict__ in,
                                                          ushort* __restrict__ out,
                                                          int R, int C) {
  __shared__ float tile[32][33];
  int tx = threadIdx.x, ty = threadIdx.y;   // block (32,8)
  int c0 = blockIdx.x * 32, r0 = blockIdx.y * 32;
#pragma unroll
  for (int k = 0; k < 4; ++k)
    tile[ty + 8 * k][tx] = in[(size_t)(r0 + ty + 8 * k) * C + c0 + tx];
  __syncthreads();
#pragma unroll
  for (int k = 0; k < 4; ++k)
    out[(size_t)(c0 + ty + 8 * k) * R + r0 + tx] = f2bf(tile[tx][ty + 8 * k]);
}

// ---------------- MFMA GEMM (m97 structure): C[M][N] = A[M][K] * BT[N][K]^T ----------------
template <typename OutT>
__global__ __launch_bounds__(256) void gemm_mfma(const ushort* __restrict__ A,
                                                 const ushort* __restrict__ BT,
                                                 OutT* __restrict__ C,
                                                 int M, int N, int K) {
  __shared__ ushort As[128 * 32];
  __shared__ ushort Bs[128 * 32];

  const int tid = threadIdx.x;
  const int w = tid >> 6, lane = tid & 63;
  const int quad = lane >> 4, l16 = lane & 15;

  // T1: XCD-aware bijective swizzle (nwg % 8 == 0 for both GEMMs here)
  int bx = blockIdx.x, by = blockIdx.y;
  {
    int nwg = gridDim.x * gridDim.y;
    if ((nwg & 7) == 0) {
      int bid = by * gridDim.x + bx;
      int chunk = nwg >> 3;
      bid = (bid & 7) * chunk + (bid >> 3);
      bx = bid % gridDim.x;
      by = bid / gridDim.x;
    }
  }
  const int m0 = by * 128, n0 = bx * 128;
  const int wm = (w & 1) * 64, wn = (w >> 1) * 64;

  f32x4 acc[4][4];
#pragma unroll
  for (int mt = 0; mt < 4; ++mt)
#pragma unroll
    for (int nt = 0; nt < 4; ++nt) acc[mt][nt] = (f32x4){0.f, 0.f, 0.f, 0.f};

  const int c0 = w * 64 + lane;
  const int r0a = c0 >> 2, k0a = (c0 & 3) * 8;
  const int c1 = 256 + c0;
  const int r1a = c1 >> 2, k1a = (c1 & 3) * 8;
  const ushort* a_src0 = A + (size_t)(m0 + r0a) * K + k0a;
  const ushort* a_src1 = A + (size_t)(m0 + r1a) * K + k1a;
  const ushort* b_src0 = BT + (size_t)(n0 + r0a) * K + k0a;
  const ushort* b_src1 = BT + (size_t)(n0 + r1a) * K + k1a;
  ushort* a_dst0 = As + (size_t)w * 512;
  ushort* a_dst1 = As + 2048 + (size_t)w * 512;
  ushort* b_dst0 = Bs + (size_t)w * 512;
  ushort* b_dst1 = Bs + 2048 + (size_t)w * 512;

  for (int k0 = 0; k0 < K; k0 += 32) {
    gld_lds16(a_src0 + k0, a_dst0);
    gld_lds16(a_src1 + k0, a_dst1);
    gld_lds16(b_src0 + k0, b_dst0);
    gld_lds16(b_src1 + k0, b_dst1);
    __syncthreads();

    bf16x8 af[4], bf[4];
#pragma unroll
    for (int mt = 0; mt < 4; ++mt)
      af[mt] = *(const bf16x8*)(As + (wm + mt * 16 + l16) * 32 + quad * 8);
#pragma unroll
    for (int nt = 0; nt < 4; ++nt)
      bf[nt] = *(const bf16x8*)(Bs + (wn + nt * 16 + l16) * 32 + quad * 8);
#pragma unroll
    for (int mt = 0; mt < 4; ++mt)
#pragma unroll
      for (int nt = 0; nt < 4; ++nt)
        acc[mt][nt] = __builtin_amdgcn_mfma_f32_16x16x32_bf16(af[mt], bf[nt], acc[mt][nt], 0, 0, 0);
    __syncthreads();
  }

#pragma unroll
  for (int mt = 0; mt < 4; ++mt) {
#pragma unroll
    for (int nt = 0; nt < 4; ++nt) {
#pragma unroll
      for (int r = 0; r < 4; ++r) {
        size_t idx = (size_t)(m0 + wm + mt * 16 + quad * 4 + r) * N + n0 + wn + nt * 16 + l16;
        if constexpr (sizeof(OutT) == 4) C[idx] = acc[mt][nt][r];
        else                             C[idx] = f2bf(acc[mt][nt][r]);
      }
    }
  }
}

// ---------------- MFMA flash attention, 32x32x16 + in-register softmax ----------------
// qkv bf16 [8192][3072]. Block = 4 waves x 32 q = 128 queries; K/V tile = 64 keys.
// Swapped QK^T at 32x32: sacc = mfma_32x32x16(K, Q) -> S^T[key][q] (col=q=lane&31,
// row=key=(reg&3)+8*(reg>>2)+4*hi). P = exp2(S) stays IN REGISTERS via T12:
// cvt_pk pairs + v_permlane32_swap_b32. Swap semantics: low lanes' B <- high lanes'
// old A; high lanes' A <- low lanes' old B. With A=d[2k2], B=d[2k2+1] both halves
// assemble fr={A0,A1,B0,B1} = P[q=lane&31][k=kb2*16+hi*8+j] (element-traced).
// L via ones-MFMA (same C-layout as O). T14: next tile's K/V global loads issue
// before PV; ds_writes at next loop-top (latency hides under PV + barrier).
#define KST 72
#define VST 72
__global__ __launch_bounds__(256, 4) void attn_mfma(const ushort* __restrict__ qkv,
                                                    ushort* __restrict__ attn_o) {
  __shared__ ushort Ks[64 * KST];        // K[key][d]
  __shared__ ushort VTs[64 * VST];       // V^T[d][key]

  const int tid = threadIdx.x;
  const int w = tid >> 6, lane = tid & 63;
  const int q32 = lane & 31, hi = lane >> 5;
  const int b = blockIdx.z, h = blockIdx.y, qb = blockIdx.x;
  const int q0 = qb * 128;

  // Q fragments (B-operand of swapped QK): lane needs Q[q=q32][d = dd*16 + hi*8 + j],
  // prescaled by 0.125 * log2(e) so P = exp2(S).
  const float qscale = 0.125f * 1.44269504088896f;
  bf16x8 qfrag[4];
  {
    const ushort* qrow = qkv + (size_t)(b * SEQ + q0 + w * 32 + q32) * 3072 + h * 64;
#pragma unroll
    for (int dd = 0; dd < 4; ++dd) {
      bf16x8 f = *(const bf16x8*)(qrow + dd * 16 + hi * 8);
#pragma unroll
      for (int j = 0; j < 8; ++j)
        f[j] = (short)f2bf(bf2f((ushort)f[j]) * qscale);
      qfrag[dd] = f;
    }
  }

  f32x16 oacc0 = zero16(), oacc1 = zero16(), lacc = zero16();

  bf16x8 ones;
#pragma unroll
  for (int j = 0; j < 8; ++j) ones[j] = (short)0x3F80;  // bf16 1.0

  // staging thread->element maps
  const int sr = tid >> 2, sc = tid & 3;   // K: row sr, 16-col group sc
  const int kp = tid & 31, dg = tid >> 5;  // V: key pair kp, 8-d group dg

  const size_t kstep = (size_t)64 * 3072;
  const ushort* kbase = qkv + (size_t)(b * SEQ + sr) * 3072 + 1024 + h * 64 + sc * 16;
  const ushort* vbase = qkv + (size_t)(b * SEQ + 2 * kp) * 3072 + 2048 + h * 64 + dg * 8;

  // T14 prologue: load tile 0 into registers
  uint4 kreg0, kreg1, vreg0, vreg1;
  {
    const uint4* ks = (const uint4*)kbase;
    kreg0 = ks[0]; kreg1 = ks[1];
    vreg0 = *(const uint4*)vbase;
    vreg1 = *(const uint4*)(vbase + 3072);
  }

  for (int kt = 0; kt < SEQ / 64; ++kt) {
    // ---- write staged regs -> LDS (vmcnt wait inserted by compiler via data dep)
    {
      uint4* kdst = (uint4*)(Ks + sr * KST + sc * 16);
      kdst[0] = kreg0; kdst[1] = kreg1;
      const ushort* ae = (const ushort*)&vreg0;
      const ushort* ce = (const ushort*)&vreg1;
#pragma unroll
      for (int j = 0; j < 8; ++j)
        *(uint*)(VTs + (dg * 8 + j) * VST + 2 * kp) = (uint)ae[j] | ((uint)ce[j] << 16);
    }
    __syncthreads();

    // ---- QK^T (swapped) + in-register softmax -> pa[kb2] PV A-fragments
    bf16x8 pa[4];
#pragma unroll
    for (int kblk = 0; kblk < 2; ++kblk) {
      f32x16 sacc = zero16();
      __builtin_amdgcn_s_setprio(1);
#pragma unroll
      for (int dd = 0; dd < 4; ++dd) {
        bf16x8 kf = *(const bf16x8*)(Ks + (kblk * 32 + q32) * KST + dd * 16 + hi * 8);
        sacc = __builtin_amdgcn_mfma_f32_32x32x16_bf16(kf, qfrag[dd], sacc, 0, 0, 0);
      }
      __builtin_amdgcn_s_setprio(0);

      // exp2 + pack: d0[p] = keys (8p+4hi+0,1), d1[p] = keys (8p+4hi+2,3), q = q32
      uint d0[4], d1[4];
#pragma unroll
      for (int p = 0; p < 4; ++p) {
        d0[p] = pk2(exp2f(sacc[4 * p + 0]), exp2f(sacc[4 * p + 1]));
        d1[p] = pk2(exp2f(sacc[4 * p + 2]), exp2f(sacc[4 * p + 3]));
      }
      // permlane32_swap(A=d[2k2], B=d[2k2+1]):
      //   low lanes:  A = own p=2k2 (kept), B = partner's p=2k2
      //   high lanes: A = partner's p=2k2+1, B = own p=2k2+1 (kept)
      // both halves: fr = {A0, A1, B0, B1} = keys kb2*16 + hi*8 + {0..7}.
#pragma unroll
      for (int k2 = 0; k2 < 2; ++k2) {
        uint A0 = d0[2 * k2], B0 = d0[2 * k2 + 1];
        uint A1 = d1[2 * k2], B1 = d1[2 * k2 + 1];
        asm("v_permlane32_swap_b32 %0, %1" : "+v"(A0), "+v"(B0));
        asm("v_permlane32_swap_b32 %0, %1" : "+v"(A1), "+v"(B1));
        uint4 fr = {A0, A1, B0, B1};
        pa[kblk * 2 + k2] = *(bf16x8*)&fr;
        lacc = __builtin_amdgcn_mfma_f32_32x32x16_bf16(pa[kblk * 2 + k2], ones, lacc, 0, 0, 0);
      }
    }

    // ---- T14: issue next tile's global loads (latency hides under PV + barrier)
    {
      int ktn = (kt + 1) & (SEQ / 64 - 1);
      const uint4* ks = (const uint4*)(kbase + ktn * kstep);
      kreg0 = ks[0]; kreg1 = ks[1];
      vreg0 = *(const uint4*)(vbase + ktn * kstep);
      vreg1 = *(const uint4*)(vbase + ktn * kstep + 3072);
    }

    // ---- O += P V : A = pa[kb2] (in regs), B = V^T rows -> V[key][d] frags
    __builtin_amdgcn_s_setprio(1);
#pragma unroll
    for (int kb2 = 0; kb2 < 4; ++kb2) {
      bf16x8 vf0 = *(const bf16x8*)(VTs + (q32)*VST + kb2 * 16 + hi * 8);
      bf16x8 vf1 = *(const bf16x8*)(VTs + (32 + q32) * VST + kb2 * 16 + hi * 8);
      oacc0 = __builtin_amdgcn_mfma_f32_32x32x16_bf16(pa[kb2], vf0, oacc0, 0, 0, 0);
      oacc1 = __builtin_amdgcn_mfma_f32_32x32x16_bf16(pa[kb2], vf1, oacc1, 0, 0, 0);
    }
    __builtin_amdgcn_s_setprio(0);
    __syncthreads();
  }

  // ---- epilogue: row = (reg&3) + 8*(reg>>2) + 4*hi, col = q32 (same layout for L)
#pragma unroll
  for (int p = 0; p < 4; ++p) {
#pragma unroll
    for (int r = 0; r < 4; ++r) {
      int qrow = r + 8 * p + 4 * hi;
      float linv = 1.0f / lacc[4 * p + r];
      ushort* orow = attn_o + (size_t)(b * SEQ + q0 + w * 32 + qrow) * 1024 + h * 64 + q32;
      orow[0]  = f2bf(oacc0[4 * p + r] * linv);
      orow[32] = f2bf(oacc1[4 * p + r] * linv);
    }
  }
}

extern "C" void kernel_launch(void* const* d_in, const int* in_sizes, int n_in,
                              void* d_out, int out_size, void* d_ws, size_t ws_size,
                              hipStream_t stream) {
  bool ok_n  = (n_in == 3);
  bool ok_s0 = ok_n && (in_sizes[0] == 4 * 2048 * 1024);
  bool ok_s1 = ok_n && (in_sizes[1] == 1024 * 3072);
  bool ok_s2 = ok_n && (in_sizes[2] == 1024 * 1024);
  bool ok_o  = (out_size == 4 * 2048 * 1024);
  bool ok_w  = (ws_size >= (size_t)8192 * 3072 * 4);
  if (!(ok_n && ok_s0 && ok_s1 && ok_s2 && ok_o && ok_w)) {
    float c = 64.0f + 1.0f * ok_n + 2.0f * ok_s0 + 4.0f * ok_s1 +
              8.0f * ok_s2 + 16.0f * ok_o + 32.0f * ok_w;
    fill_f32<<<(out_size + 255) / 256, 256, 0, stream>>>((float*)d_out, out_size, c);
    return;
  }

  const float* x     = (const float*)d_in[0];  // [8192][1024]
  const float* w_qkv = (const float*)d_in[1];  // [1024][3072]
  const float* w_out = (const float*)d_in[2];  // [1024][1024]

  char* ws = (char*)d_ws;
  ushort* qkv    = (ushort*)ws;                                  // 48 MB
  ushort* xb     = (ushort*)(ws + (size_t)48 * 1024 * 1024);     // 16 MB
  ushort* attn_o = (ushort*)(ws + (size_t)64 * 1024 * 1024);     // 16 MB
  ushort* wqkvT  = (ushort*)(ws + (size_t)80 * 1024 * 1024);     // 6 MB
  ushort* woutT  = (ushort*)(ws + (size_t)86 * 1024 * 1024);     // 2 MB

  cast_bf16<<<dim3(8192 * 1024 / 8 / 256), dim3(256), 0, stream>>>(x, xb, 8192 * 1024 / 8);
  transpose_f32_bf16<<<dim3(3072 / 32, 1024 / 32), dim3(32, 8), 0, stream>>>(w_qkv, wqkvT, 1024, 3072);
  transpose_f32_bf16<<<dim3(1024 / 32, 1024 / 32), dim3(32, 8), 0, stream>>>(w_out, woutT, 1024, 1024);

  gemm_mfma<ushort><<<dim3(3072 / 128, 8192 / 128), dim3(256), 0, stream>>>(
      xb, wqkvT, qkv, 8192, 3072, 1024);

  attn_mfma<<<dim3(SEQ / 128, NHEAD, BATCH), dim3(256), 0, stream>>>(qkv, attn_o);

  gemm_mfma<float><<<dim3(1024 / 128, 8192 / 128), dim3(256), 0, stream>>>(
      attn_o, woutT, (float*)d_out, 8192, 1024, 1024);
}

// Round 4
// 303.788 us; speedup vs baseline: 1.0126x; 1.0126x over previous
//
#include <hip/hip_runtime.h>
#include <hip/hip_bf16.h>
#include <math.h>

#define D_MODEL 1024
#define NHEAD   16
#define HEAD_DIM 64
#define BATCH   4
#define SEQ     2048

typedef __attribute__((ext_vector_type(8))) short bf16x8;
typedef __attribute__((ext_vector_type(4))) float f32x4;
typedef __attribute__((ext_vector_type(16))) float f32x16;

__device__ inline ushort f2bf(float f) {
  __hip_bfloat16 h = __float2bfloat16(f);
  return *reinterpret_cast<ushort*>(&h);
}
__device__ inline uint pk2(float a, float b) {
  return (uint)f2bf(a) | ((uint)f2bf(b) << 16);
}
__device__ inline float bf2f(ushort u) {
  return __uint_as_float((uint)u << 16);
}
__device__ inline f32x16 zero16() {
  f32x16 z;
#pragma unroll
  for (int i = 0; i < 16; ++i) z[i] = 0.f;
  return z;
}
// async 16B global -> LDS (dest = wave-uniform base + lane*16; LDS must be unpadded)
__device__ inline void gld_lds16(const ushort* g, ushort* l) {
  __builtin_amdgcn_global_load_lds(
      (const __attribute__((address_space(1))) void*)g,
      (__attribute__((address_space(3))) void*)l, 16, 0, 0);
}

// ---------------- diagnostic fill ----------------
__global__ __launch_bounds__(256) void fill_f32(float* __restrict__ p, int n, float v) {
  int i = blockIdx.x * 256 + threadIdx.x;
  if (i < n) p[i] = v;
}

// ---------------- x: fp32 -> bf16 (8 elems/thread) ----------------
__global__ __launch_bounds__(256) void cast_bf16(const float* __restrict__ in,
                                                 ushort* __restrict__ out, int n8) {
  int i = blockIdx.x * 256 + threadIdx.x;
  if (i >= n8) return;
  const float4* p = (const float4*)(in + i * 8);
  float4 a = p[0], b = p[1];
  uint4 o;
  o.x = pk2(a.x, a.y); o.y = pk2(a.z, a.w);
  o.z = pk2(b.x, b.y); o.w = pk2(b.z, b.w);
  ((uint4*)out)[i] = o;
}

// ---------------- fp32 -> bf16 transpose: in[R][C] f32 -> out[C][R] bf16 ----------------
__global__ __launch_bounds__(256) void transpose_f32_bf16(const float* __restrict__ in,
                                                          ushort* __restrict__ out,
                                                          int R, int C) {
  __shared__ float tile[32][33];
  int tx = threadIdx.x, ty = threadIdx.y;   // block (32,8)
  int c0 = blockIdx.x * 32, r0 = blockIdx.y * 32;
#pragma unroll
  for (int k = 0; k < 4; ++k)
    tile[ty + 8 * k][tx] = in[(size_t)(r0 + ty + 8 * k) * C + c0 + tx];
  __syncthreads();
#pragma unroll
  for (int k = 0; k < 4; ++k)
    out[(size_t)(c0 + ty + 8 * k) * R + r0 + tx] = f2bf(tile[tx][ty + 8 * k]);
}

// ---------------- MFMA GEMM (m97 structure): C[M][N] = A[M][K] * BT[N][K]^T ----------------
template <typename OutT>
__global__ __launch_bounds__(256) void gemm_mfma(const ushort* __restrict__ A,
                                                 const ushort* __restrict__ BT,
                                                 OutT* __restrict__ C,
                                                 int M, int N, int K) {
  __shared__ ushort As[128 * 32];
  __shared__ ushort Bs[128 * 32];

  const int tid = threadIdx.x;
  const int w = tid >> 6, lane = tid & 63;
  const int quad = lane >> 4, l16 = lane & 15;

  // T1: XCD-aware bijective swizzle (nwg % 8 == 0 for both GEMMs here)
  int bx = blockIdx.x, by = blockIdx.y;
  {
    int nwg = gridDim.x * gridDim.y;
    if ((nwg & 7) == 0) {
      int bid = by * gridDim.x + bx;
      int chunk = nwg >> 3;
      bid = (bid & 7) * chunk + (bid >> 3);
      bx = bid % gridDim.x;
      by = bid / gridDim.x;
    }
  }
  const int m0 = by * 128, n0 = bx * 128;
  const int wm = (w & 1) * 64, wn = (w >> 1) * 64;

  f32x4 acc[4][4];
#pragma unroll
  for (int mt = 0; mt < 4; ++mt)
#pragma unroll
    for (int nt = 0; nt < 4; ++nt) acc[mt][nt] = (f32x4){0.f, 0.f, 0.f, 0.f};

  const int c0 = w * 64 + lane;
  const int r0a = c0 >> 2, k0a = (c0 & 3) * 8;
  const int c1 = 256 + c0;
  const int r1a = c1 >> 2, k1a = (c1 & 3) * 8;
  const ushort* a_src0 = A + (size_t)(m0 + r0a) * K + k0a;
  const ushort* a_src1 = A + (size_t)(m0 + r1a) * K + k1a;
  const ushort* b_src0 = BT + (size_t)(n0 + r0a) * K + k0a;
  const ushort* b_src1 = BT + (size_t)(n0 + r1a) * K + k1a;
  ushort* a_dst0 = As + (size_t)w * 512;
  ushort* a_dst1 = As + 2048 + (size_t)w * 512;
  ushort* b_dst0 = Bs + (size_t)w * 512;
  ushort* b_dst1 = Bs + 2048 + (size_t)w * 512;

  for (int k0 = 0; k0 < K; k0 += 32) {
    gld_lds16(a_src0 + k0, a_dst0);
    gld_lds16(a_src1 + k0, a_dst1);
    gld_lds16(b_src0 + k0, b_dst0);
    gld_lds16(b_src1 + k0, b_dst1);
    __syncthreads();

    bf16x8 af[4], bf[4];
#pragma unroll
    for (int mt = 0; mt < 4; ++mt)
      af[mt] = *(const bf16x8*)(As + (wm + mt * 16 + l16) * 32 + quad * 8);
#pragma unroll
    for (int nt = 0; nt < 4; ++nt)
      bf[nt] = *(const bf16x8*)(Bs + (wn + nt * 16 + l16) * 32 + quad * 8);
#pragma unroll
    for (int mt = 0; mt < 4; ++mt)
#pragma unroll
      for (int nt = 0; nt < 4; ++nt)
        acc[mt][nt] = __builtin_amdgcn_mfma_f32_16x16x32_bf16(af[mt], bf[nt], acc[mt][nt], 0, 0, 0);
    __syncthreads();
  }

#pragma unroll
  for (int mt = 0; mt < 4; ++mt) {
#pragma unroll
    for (int nt = 0; nt < 4; ++nt) {
#pragma unroll
      for (int r = 0; r < 4; ++r) {
        size_t idx = (size_t)(m0 + wm + mt * 16 + quad * 4 + r) * N + n0 + wn + nt * 16 + l16;
        if constexpr (sizeof(OutT) == 4) C[idx] = acc[mt][nt][r];
        else                             C[idx] = f2bf(acc[mt][nt][r]);
      }
    }
  }
}

// ---------------- MFMA flash attention, 32x32x16 + in-register softmax ----------------
// qkv bf16 [8192][3072]. Block = 4 waves x 32 q = 128 queries; K/V tile = 64 keys.
// Swapped QK^T at 32x32 -> S^T[key][q]; P = exp2(S) in registers (T12: cvt_pk pairs +
// v_permlane32_swap_b32, element-traced in R2). L via ones-MFMA (same C layout as O).
// R3: (a) DOUBLE-BUFFERED K/V LDS -> single barrier per K-tile; stage-write moved
// after PV (overlaps MFMA). Race audit: writes to buf[cur^1]@iter t vs reads@t+1
// separated by loop-top barrier; within iter, reads buf[cur] / writes buf[cur^1].
// (b) prefetch issue at loop-top: global->reg loads get QK+softmax+PV to land.
// (c) XCD-chunked 1-D grid: all 16 q-blocks of a head on one XCD (per-XCD K/V
// working set = 8 heads x 512KB = 4MB = L2).
#define KST 72
#define VST 72
#define NT  (SEQ / 64)
__global__ __launch_bounds__(256, 4) void attn_mfma(const ushort* __restrict__ qkv,
                                                    ushort* __restrict__ attn_o) {
  __shared__ ushort Ks[2][64 * KST];     // K[key][d]
  __shared__ ushort VTs[2][64 * VST];    // V^T[d][key]

  const int tid = threadIdx.x;
  const int w = tid >> 6, lane = tid & 63;
  const int q32 = lane & 31, hi = lane >> 5;

  // XCD-chunked swizzle (bijective): f -> (xcd, slot); head hb = slot_hi*8 + xcd,
  // all 16 qb of that head contiguous on one XCD (assuming round-robin f%8 -> XCD).
  const int f = blockIdx.x;
  const int xcd = f & 7;
  const int j = f >> 3;                  // 0..127
  const int qb = j & 15;
  const int hb = ((j >> 4) << 3) | xcd;  // 0..63
  const int h = hb & 15, b = hb >> 4;
  const int q0 = qb * 128;

  // Q fragments (B-operand of swapped QK): lane needs Q[q=q32][d = dd*16 + hi*8 + j],
  // prescaled by 0.125 * log2(e) so P = exp2(S).
  const float qscale = 0.125f * 1.44269504088896f;
  bf16x8 qfrag[4];
  {
    const ushort* qrow = qkv + (size_t)(b * SEQ + q0 + w * 32 + q32) * 3072 + h * 64;
#pragma unroll
    for (int dd = 0; dd < 4; ++dd) {
      bf16x8 fq = *(const bf16x8*)(qrow + dd * 16 + hi * 8);
#pragma unroll
      for (int jj = 0; jj < 8; ++jj)
        fq[jj] = (short)f2bf(bf2f((ushort)fq[jj]) * qscale);
      qfrag[dd] = fq;
    }
  }

  f32x16 oacc0 = zero16(), oacc1 = zero16(), lacc = zero16();

  bf16x8 ones;
#pragma unroll
  for (int jj = 0; jj < 8; ++jj) ones[jj] = (short)0x3F80;  // bf16 1.0

  // staging thread->element maps
  const int sr = tid >> 2, sc = tid & 3;   // K: row sr, 16-col group sc
  const int kp = tid & 31, dg = tid >> 5;  // V: key pair kp, 8-d group dg

  const size_t kstep = (size_t)64 * 3072;
  const ushort* kbase = qkv + (size_t)(b * SEQ + sr) * 3072 + 1024 + h * 64 + sc * 16;
  const ushort* vbase = qkv + (size_t)(b * SEQ + 2 * kp) * 3072 + 2048 + h * 64 + dg * 8;

  // prologue: load tile 0 -> regs -> buf0 (loop-top barrier covers the writes)
  uint4 kreg0, kreg1, vreg0, vreg1;
  {
    const uint4* ks = (const uint4*)kbase;
    kreg0 = ks[0]; kreg1 = ks[1];
    vreg0 = *(const uint4*)vbase;
    vreg1 = *(const uint4*)(vbase + 3072);
    uint4* kdst = (uint4*)(Ks[0] + sr * KST + sc * 16);
    kdst[0] = kreg0; kdst[1] = kreg1;
    const ushort* ae = (const ushort*)&vreg0;
    const ushort* ce = (const ushort*)&vreg1;
#pragma unroll
    for (int jj = 0; jj < 8; ++jj)
      *(uint*)(VTs[0] + (dg * 8 + jj) * VST + 2 * kp) = (uint)ae[jj] | ((uint)ce[jj] << 16);
  }

  for (int kt = 0; kt < NT; ++kt) {
    const int cur = kt & 1;
    __syncthreads();   // writes of buf[cur] (prev iter / prologue) complete

    // ---- prefetch issue: tile kt+1 -> regs (lands during QK+softmax+PV)
    if (kt + 1 < NT) {
      const uint4* ks = (const uint4*)(kbase + (size_t)(kt + 1) * kstep);
      kreg0 = ks[0]; kreg1 = ks[1];
      vreg0 = *(const uint4*)(vbase + (size_t)(kt + 1) * kstep);
      vreg1 = *(const uint4*)(vbase + (size_t)(kt + 1) * kstep + 3072);
    }

    // ---- QK^T (swapped) + in-register softmax -> pa[kb2] PV A-fragments
    bf16x8 pa[4];
#pragma unroll
    for (int kblk = 0; kblk < 2; ++kblk) {
      f32x16 sacc = zero16();
      __builtin_amdgcn_s_setprio(1);
#pragma unroll
      for (int dd = 0; dd < 4; ++dd) {
        bf16x8 kf = *(const bf16x8*)(Ks[cur] + (kblk * 32 + q32) * KST + dd * 16 + hi * 8);
        sacc = __builtin_amdgcn_mfma_f32_32x32x16_bf16(kf, qfrag[dd], sacc, 0, 0, 0);
      }
      __builtin_amdgcn_s_setprio(0);

      // exp2 + pack: d0[p] = keys (8p+4hi+0,1), d1[p] = keys (8p+4hi+2,3), q = q32
      uint d0[4], d1[4];
#pragma unroll
      for (int p = 0; p < 4; ++p) {
        d0[p] = pk2(exp2f(sacc[4 * p + 0]), exp2f(sacc[4 * p + 1]));
        d1[p] = pk2(exp2f(sacc[4 * p + 2]), exp2f(sacc[4 * p + 3]));
      }
      // permlane32_swap(A=d[2k2], B=d[2k2+1]):
      //   low lanes:  A = own p=2k2 (kept), B = partner's p=2k2
      //   high lanes: A = partner's p=2k2+1, B = own p=2k2+1 (kept)
      // both halves: fr = {A0, A1, B0, B1} = keys kb2*16 + hi*8 + {0..7}.
#pragma unroll
      for (int k2 = 0; k2 < 2; ++k2) {
        uint A0 = d0[2 * k2], B0 = d0[2 * k2 + 1];
        uint A1 = d1[2 * k2], B1 = d1[2 * k2 + 1];
        asm("v_permlane32_swap_b32 %0, %1" : "+v"(A0), "+v"(B0));
        asm("v_permlane32_swap_b32 %0, %1" : "+v"(A1), "+v"(B1));
        uint4 fr = {A0, A1, B0, B1};
        pa[kblk * 2 + k2] = *(bf16x8*)&fr;
        lacc = __builtin_amdgcn_mfma_f32_32x32x16_bf16(pa[kblk * 2 + k2], ones, lacc, 0, 0, 0);
      }
    }

    // ---- O += P V : A = pa[kb2] (in regs), B = V^T rows -> V[key][d] frags
    __builtin_amdgcn_s_setprio(1);
#pragma unroll
    for (int kb2 = 0; kb2 < 4; ++kb2) {
      bf16x8 vf0 = *(const bf16x8*)(VTs[cur] + (q32)*VST + kb2 * 16 + hi * 8);
      bf16x8 vf1 = *(const bf16x8*)(VTs[cur] + (32 + q32) * VST + kb2 * 16 + hi * 8);
      oacc0 = __builtin_amdgcn_mfma_f32_32x32x16_bf16(pa[kb2], vf0, oacc0, 0, 0, 0);
      oacc1 = __builtin_amdgcn_mfma_f32_32x32x16_bf16(pa[kb2], vf1, oacc1, 0, 0, 0);
    }
    __builtin_amdgcn_s_setprio(0);

    // ---- stage-write: regs (tile kt+1) -> buf[cur^1]; overlaps with other waves'
    // PV (no barrier between PV and this). vmcnt waits come from reg data deps.
    if (kt + 1 < NT) {
      uint4* kdst = (uint4*)(Ks[cur ^ 1] + sr * KST + sc * 16);
      kdst[0] = kreg0; kdst[1] = kreg1;
      const ushort* ae = (const ushort*)&vreg0;
      const ushort* ce = (const ushort*)&vreg1;
#pragma unroll
      for (int jj = 0; jj < 8; ++jj)
        *(uint*)(VTs[cur ^ 1] + (dg * 8 + jj) * VST + 2 * kp) = (uint)ae[jj] | ((uint)ce[jj] << 16);
    }
  }

  // ---- epilogue: row = (reg&3) + 8*(reg>>2) + 4*hi, col = q32 (same layout for L)
#pragma unroll
  for (int p = 0; p < 4; ++p) {
#pragma unroll
    for (int r = 0; r < 4; ++r) {
      int qrow = r + 8 * p + 4 * hi;
      float linv = 1.0f / lacc[4 * p + r];
      ushort* orow = attn_o + (size_t)(b * SEQ + q0 + w * 32 + qrow) * 1024 + h * 64 + q32;
      orow[0]  = f2bf(oacc0[4 * p + r] * linv);
      orow[32] = f2bf(oacc1[4 * p + r] * linv);
    }
  }
}

extern "C" void kernel_launch(void* const* d_in, const int* in_sizes, int n_in,
                              void* d_out, int out_size, void* d_ws, size_t ws_size,
                              hipStream_t stream) {
  bool ok_n  = (n_in == 3);
  bool ok_s0 = ok_n && (in_sizes[0] == 4 * 2048 * 1024);
  bool ok_s1 = ok_n && (in_sizes[1] == 1024 * 3072);
  bool ok_s2 = ok_n && (in_sizes[2] == 1024 * 1024);
  bool ok_o  = (out_size == 4 * 2048 * 1024);
  bool ok_w  = (ws_size >= (size_t)8192 * 3072 * 4);
  if (!(ok_n && ok_s0 && ok_s1 && ok_s2 && ok_o && ok_w)) {
    float c = 64.0f + 1.0f * ok_n + 2.0f * ok_s0 + 4.0f * ok_s1 +
              8.0f * ok_s2 + 16.0f * ok_o + 32.0f * ok_w;
    fill_f32<<<(out_size + 255) / 256, 256, 0, stream>>>((float*)d_out, out_size, c);
    return;
  }

  const float* x     = (const float*)d_in[0];  // [8192][1024]
  const float* w_qkv = (const float*)d_in[1];  // [1024][3072]
  const float* w_out = (const float*)d_in[2];  // [1024][1024]

  char* ws = (char*)d_ws;
  ushort* qkv    = (ushort*)ws;                                  // 48 MB
  ushort* xb     = (ushort*)(ws + (size_t)48 * 1024 * 1024);     // 16 MB
  ushort* attn_o = (ushort*)(ws + (size_t)64 * 1024 * 1024);     // 16 MB
  ushort* wqkvT  = (ushort*)(ws + (size_t)80 * 1024 * 1024);     // 6 MB
  ushort* woutT  = (ushort*)(ws + (size_t)86 * 1024 * 1024);     // 2 MB

  cast_bf16<<<dim3(8192 * 1024 / 8 / 256), dim3(256), 0, stream>>>(x, xb, 8192 * 1024 / 8);
  transpose_f32_bf16<<<dim3(3072 / 32, 1024 / 32), dim3(32, 8), 0, stream>>>(w_qkv, wqkvT, 1024, 3072);
  transpose_f32_bf16<<<dim3(1024 / 32, 1024 / 32), dim3(32, 8), 0, stream>>>(w_out, woutT, 1024, 1024);

  gemm_mfma<ushort><<<dim3(3072 / 128, 8192 / 128), dim3(256), 0, stream>>>(
      xb, wqkvT, qkv, 8192, 3072, 1024);

  attn_mfma<<<dim3(1024), dim3(256), 0, stream>>>(qkv, attn_o);

  gemm_mfma<float><<<dim3(1024 / 128, 8192 / 128), dim3(256), 0, stream>>>(
      attn_o, woutT, (float*)d_out, 8192, 1024, 1024);
}

// Round 5
// 289.336 us; speedup vs baseline: 1.0632x; 1.0499x over previous
//
#include <hip/hip_runtime.h>
#include <hip/hip_bf16.h>
#include <math.h>

#define D_MODEL 1024
#define NHEAD   16
#define HEAD_DIM 64
#define BATCH   4
#define SEQ     2048

typedef __attribute__((ext_vector_type(8))) short bf16x8;
typedef __attribute__((ext_vector_type(4))) float f32x4;
typedef __attribute__((ext_vector_type(16))) float f32x16;

__device__ inline ushort f2bf(float f) {
  __hip_bfloat16 h = __float2bfloat16(f);
  return *reinterpret_cast<ushort*>(&h);
}
__device__ inline uint pk2(float a, float b) {
  return (uint)f2bf(a) | ((uint)f2bf(b) << 16);
}
__device__ inline float bf2f(ushort u) {
  return __uint_as_float((uint)u << 16);
}
__device__ inline f32x16 zero16() {
  f32x16 z;
#pragma unroll
  for (int i = 0; i < 16; ++i) z[i] = 0.f;
  return z;
}
// raw v_exp_f32 (2^x), no denormal-guard wrapper (logits are O(1))
__device__ inline float fexp2(float x) { return __builtin_amdgcn_exp2f(x); }

// async 16B global -> LDS (dest = wave-uniform base + lane*16; LDS must be unpadded)
__device__ inline void gld_lds16(const ushort* g, ushort* l) {
  __builtin_amdgcn_global_load_lds(
      (const __attribute__((address_space(1))) void*)g,
      (__attribute__((address_space(3))) void*)l, 16, 0, 0);
}

// ---------------- diagnostic fill ----------------
__global__ __launch_bounds__(256) void fill_f32(float* __restrict__ p, int n, float v) {
  int i = blockIdx.x * 256 + threadIdx.x;
  if (i < n) p[i] = v;
}

// ---------------- x: fp32 -> bf16 (8 elems/thread) ----------------
__global__ __launch_bounds__(256) void cast_bf16(const float* __restrict__ in,
                                                 ushort* __restrict__ out, int n8) {
  int i = blockIdx.x * 256 + threadIdx.x;
  if (i >= n8) return;
  const float4* p = (const float4*)(in + i * 8);
  float4 a = p[0], b = p[1];
  uint4 o;
  o.x = pk2(a.x, a.y); o.y = pk2(a.z, a.w);
  o.z = pk2(b.x, b.y); o.w = pk2(b.z, b.w);
  ((uint4*)out)[i] = o;
}

// ---------------- fp32 -> bf16 transpose: in[R][C] f32 -> out[C][R] bf16 ----------------
__global__ __launch_bounds__(256) void transpose_f32_bf16(const float* __restrict__ in,
                                                          ushort* __restrict__ out,
                                                          int R, int C) {
  __shared__ float tile[32][33];
  int tx = threadIdx.x, ty = threadIdx.y;   // block (32,8)
  int c0 = blockIdx.x * 32, r0 = blockIdx.y * 32;
#pragma unroll
  for (int k = 0; k < 4; ++k)
    tile[ty + 8 * k][tx] = in[(size_t)(r0 + ty + 8 * k) * C + c0 + tx];
  __syncthreads();
#pragma unroll
  for (int k = 0; k < 4; ++k)
    out[(size_t)(c0 + ty + 8 * k) * R + r0 + tx] = f2bf(tile[tx][ty + 8 * k]);
}

// ---------------- MFMA GEMM (m97 structure): C[M][N] = A[M][K] * BT[N][K]^T ----------------
template <typename OutT>
__global__ __launch_bounds__(256) void gemm_mfma(const ushort* __restrict__ A,
                                                 const ushort* __restrict__ BT,
                                                 OutT* __restrict__ C,
                                                 int M, int N, int K) {
  __shared__ ushort As[128 * 32];
  __shared__ ushort Bs[128 * 32];

  const int tid = threadIdx.x;
  const int w = tid >> 6, lane = tid & 63;
  const int quad = lane >> 4, l16 = lane & 15;

  // T1: XCD-aware bijective swizzle (nwg % 8 == 0 for both GEMMs here)
  int bx = blockIdx.x, by = blockIdx.y;
  {
    int nwg = gridDim.x * gridDim.y;
    if ((nwg & 7) == 0) {
      int bid = by * gridDim.x + bx;
      int chunk = nwg >> 3;
      bid = (bid & 7) * chunk + (bid >> 3);
      bx = bid % gridDim.x;
      by = bid / gridDim.x;
    }
  }
  const int m0 = by * 128, n0 = bx * 128;
  const int wm = (w & 1) * 64, wn = (w >> 1) * 64;

  f32x4 acc[4][4];
#pragma unroll
  for (int mt = 0; mt < 4; ++mt)
#pragma unroll
    for (int nt = 0; nt < 4; ++nt) acc[mt][nt] = (f32x4){0.f, 0.f, 0.f, 0.f};

  const int c0 = w * 64 + lane;
  const int r0a = c0 >> 2, k0a = (c0 & 3) * 8;
  const int c1 = 256 + c0;
  const int r1a = c1 >> 2, k1a = (c1 & 3) * 8;
  const ushort* a_src0 = A + (size_t)(m0 + r0a) * K + k0a;
  const ushort* a_src1 = A + (size_t)(m0 + r1a) * K + k1a;
  const ushort* b_src0 = BT + (size_t)(n0 + r0a) * K + k0a;
  const ushort* b_src1 = BT + (size_t)(n0 + r1a) * K + k1a;
  ushort* a_dst0 = As + (size_t)w * 512;
  ushort* a_dst1 = As + 2048 + (size_t)w * 512;
  ushort* b_dst0 = Bs + (size_t)w * 512;
  ushort* b_dst1 = Bs + 2048 + (size_t)w * 512;

  for (int k0 = 0; k0 < K; k0 += 32) {
    gld_lds16(a_src0 + k0, a_dst0);
    gld_lds16(a_src1 + k0, a_dst1);
    gld_lds16(b_src0 + k0, b_dst0);
    gld_lds16(b_src1 + k0, b_dst1);
    __syncthreads();

    bf16x8 af[4], bf[4];
#pragma unroll
    for (int mt = 0; mt < 4; ++mt)
      af[mt] = *(const bf16x8*)(As + (wm + mt * 16 + l16) * 32 + quad * 8);
#pragma unroll
    for (int nt = 0; nt < 4; ++nt)
      bf[nt] = *(const bf16x8*)(Bs + (wn + nt * 16 + l16) * 32 + quad * 8);
#pragma unroll
    for (int mt = 0; mt < 4; ++mt)
#pragma unroll
      for (int nt = 0; nt < 4; ++nt)
        acc[mt][nt] = __builtin_amdgcn_mfma_f32_16x16x32_bf16(af[mt], bf[nt], acc[mt][nt], 0, 0, 0);
    __syncthreads();
  }

#pragma unroll
  for (int mt = 0; mt < 4; ++mt) {
#pragma unroll
    for (int nt = 0; nt < 4; ++nt) {
#pragma unroll
      for (int r = 0; r < 4; ++r) {
        size_t idx = (size_t)(m0 + wm + mt * 16 + quad * 4 + r) * N + n0 + wn + nt * 16 + l16;
        if constexpr (sizeof(OutT) == 4) C[idx] = acc[mt][nt][r];
        else                             C[idx] = f2bf(acc[mt][nt][r]);
      }
    }
  }
}

// ---------------- MFMA flash attention, 32x32x16 + in-register softmax ----------------
// qkv bf16 [8192][3072]. Block = 4 waves x 32 q = 128 queries; K/V tile = 64 keys.
// Swapped QK^T at 32x32 -> S^T[key][q]; P = exp2(S) in registers (T12: cvt_pk pairs +
// v_permlane32_swap_b32, element-traced in R2). L via ones-MFMA (same C layout as O).
// Structure (R3, verified): dbuf K/V LDS, 1 barrier/iter, loop-top prefetch issue,
// post-PV stage-write, XCD-chunked 1-D grid (FETCH 143->24.6MB).
// R4 (VALU trim -- VALUBusy was 67%, the hottest pipe):
//  (a) V^T staged via direct ushort stores (ds_write_b16/_d16_hi) -- no pack VALU
//  (b) QK kblk0+kblk1 MFMA chains issued before softmax (ILP: SM0 overlaps QK1)
//  (c) raw v_exp via __builtin_amdgcn_exp2f (no denormal-guard wrapper)
#define KST 72
#define VST 72
#define NT  (SEQ / 64)
__global__ __launch_bounds__(256, 4) void attn_mfma(const ushort* __restrict__ qkv,
                                                    ushort* __restrict__ attn_o) {
  __shared__ ushort Ks[2][64 * KST];     // K[key][d]
  __shared__ ushort VTs[2][64 * VST];    // V^T[d][key]

  const int tid = threadIdx.x;
  const int w = tid >> 6, lane = tid & 63;
  const int q32 = lane & 31, hi = lane >> 5;

  // XCD-chunked swizzle (bijective): all 16 q-blocks of a head on one XCD.
  const int f = blockIdx.x;
  const int xcd = f & 7;
  const int j = f >> 3;                  // 0..127
  const int qb = j & 15;
  const int hb = ((j >> 4) << 3) | xcd;  // 0..63
  const int h = hb & 15, b = hb >> 4;
  const int q0 = qb * 128;

  // Q fragments (B-operand of swapped QK): lane needs Q[q=q32][d = dd*16 + hi*8 + j],
  // prescaled by 0.125 * log2(e) so P = exp2(S).
  const float qscale = 0.125f * 1.44269504088896f;
  bf16x8 qfrag[4];
  {
    const ushort* qrow = qkv + (size_t)(b * SEQ + q0 + w * 32 + q32) * 3072 + h * 64;
#pragma unroll
    for (int dd = 0; dd < 4; ++dd) {
      bf16x8 fq = *(const bf16x8*)(qrow + dd * 16 + hi * 8);
#pragma unroll
      for (int jj = 0; jj < 8; ++jj)
        fq[jj] = (short)f2bf(bf2f((ushort)fq[jj]) * qscale);
      qfrag[dd] = fq;
    }
  }

  f32x16 oacc0 = zero16(), oacc1 = zero16(), lacc = zero16();

  bf16x8 ones;
#pragma unroll
  for (int jj = 0; jj < 8; ++jj) ones[jj] = (short)0x3F80;  // bf16 1.0

  // staging thread->element maps
  const int sr = tid >> 2, sc = tid & 3;   // K: row sr, 16-col group sc
  const int kp = tid & 31, dg = tid >> 5;  // V: key pair kp, 8-d group dg

  const size_t kstep = (size_t)64 * 3072;
  const ushort* kbase = qkv + (size_t)(b * SEQ + sr) * 3072 + 1024 + h * 64 + sc * 16;
  const ushort* vbase = qkv + (size_t)(b * SEQ + 2 * kp) * 3072 + 2048 + h * 64 + dg * 8;

  // prologue: load tile 0 -> regs -> buf0 (loop-top barrier covers the writes)
  uint4 kreg0, kreg1, vreg0, vreg1;
  {
    const uint4* ks = (const uint4*)kbase;
    kreg0 = ks[0]; kreg1 = ks[1];
    vreg0 = *(const uint4*)vbase;
    vreg1 = *(const uint4*)(vbase + 3072);
    uint4* kdst = (uint4*)(Ks[0] + sr * KST + sc * 16);
    kdst[0] = kreg0; kdst[1] = kreg1;
    const ushort* ae = (const ushort*)&vreg0;
    const ushort* ce = (const ushort*)&vreg1;
#pragma unroll
    for (int jj = 0; jj < 8; ++jj) {
      VTs[0][(dg * 8 + jj) * VST + 2 * kp]     = ae[jj];
      VTs[0][(dg * 8 + jj) * VST + 2 * kp + 1] = ce[jj];
    }
  }

  for (int kt = 0; kt < NT; ++kt) {
    const int cur = kt & 1;
    __syncthreads();   // writes of buf[cur] (prev iter / prologue) complete

    // ---- prefetch issue: tile kt+1 -> regs (lands during QK+softmax+PV)
    if (kt + 1 < NT) {
      const uint4* ks = (const uint4*)(kbase + (size_t)(kt + 1) * kstep);
      kreg0 = ks[0]; kreg1 = ks[1];
      vreg0 = *(const uint4*)(vbase + (size_t)(kt + 1) * kstep);
      vreg1 = *(const uint4*)(vbase + (size_t)(kt + 1) * kstep + 3072);
    }

    // ---- QK^T (swapped), both 32-key halves first (ILP: SM0 can overlap QK1)
    f32x16 sacc0 = zero16(), sacc1 = zero16();
    __builtin_amdgcn_s_setprio(1);
#pragma unroll
    for (int dd = 0; dd < 4; ++dd) {
      bf16x8 kf0 = *(const bf16x8*)(Ks[cur] + (q32)*KST + dd * 16 + hi * 8);
      bf16x8 kf1 = *(const bf16x8*)(Ks[cur] + (32 + q32) * KST + dd * 16 + hi * 8);
      sacc0 = __builtin_amdgcn_mfma_f32_32x32x16_bf16(kf0, qfrag[dd], sacc0, 0, 0, 0);
      sacc1 = __builtin_amdgcn_mfma_f32_32x32x16_bf16(kf1, qfrag[dd], sacc1, 0, 0, 0);
    }
    __builtin_amdgcn_s_setprio(0);

    // ---- in-register softmax -> pa[kb2] PV A-fragments
    bf16x8 pa[4];
#pragma unroll
    for (int kblk = 0; kblk < 2; ++kblk) {
      const f32x16& sacc = kblk ? sacc1 : sacc0;
      // exp2 + pack: d0[p] = keys (8p+4hi+0,1), d1[p] = keys (8p+4hi+2,3), q = q32
      uint d0[4], d1[4];
#pragma unroll
      for (int p = 0; p < 4; ++p) {
        d0[p] = pk2(fexp2(sacc[4 * p + 0]), fexp2(sacc[4 * p + 1]));
        d1[p] = pk2(fexp2(sacc[4 * p + 2]), fexp2(sacc[4 * p + 3]));
      }
      // permlane32_swap(A=d[2k2], B=d[2k2+1]):
      //   low lanes:  A = own p=2k2 (kept), B = partner's p=2k2
      //   high lanes: A = partner's p=2k2+1, B = own p=2k2+1 (kept)
      // both halves: fr = {A0, A1, B0, B1} = keys kb2*16 + hi*8 + {0..7}.
#pragma unroll
      for (int k2 = 0; k2 < 2; ++k2) {
        uint A0 = d0[2 * k2], B0 = d0[2 * k2 + 1];
        uint A1 = d1[2 * k2], B1 = d1[2 * k2 + 1];
        asm("v_permlane32_swap_b32 %0, %1" : "+v"(A0), "+v"(B0));
        asm("v_permlane32_swap_b32 %0, %1" : "+v"(A1), "+v"(B1));
        uint4 fr = {A0, A1, B0, B1};
        pa[kblk * 2 + k2] = *(bf16x8*)&fr;
        lacc = __builtin_amdgcn_mfma_f32_32x32x16_bf16(pa[kblk * 2 + k2], ones, lacc, 0, 0, 0);
      }
    }

    // ---- O += P V : A = pa[kb2] (in regs), B = V^T rows -> V[key][d] frags
    __builtin_amdgcn_s_setprio(1);
#pragma unroll
    for (int kb2 = 0; kb2 < 4; ++kb2) {
      bf16x8 vf0 = *(const bf16x8*)(VTs[cur] + (q32)*VST + kb2 * 16 + hi * 8);
      bf16x8 vf1 = *(const bf16x8*)(VTs[cur] + (32 + q32) * VST + kb2 * 16 + hi * 8);
      oacc0 = __builtin_amdgcn_mfma_f32_32x32x16_bf16(pa[kb2], vf0, oacc0, 0, 0, 0);
      oacc1 = __builtin_amdgcn_mfma_f32_32x32x16_bf16(pa[kb2], vf1, oacc1, 0, 0, 0);
    }
    __builtin_amdgcn_s_setprio(0);

    // ---- stage-write: regs (tile kt+1) -> buf[cur^1]; overlaps other waves' PV.
    // V^T written as direct b16 stores (d16_hi for high halves) -- no pack VALU.
    if (kt + 1 < NT) {
      uint4* kdst = (uint4*)(Ks[cur ^ 1] + sr * KST + sc * 16);
      kdst[0] = kreg0; kdst[1] = kreg1;
      const ushort* ae = (const ushort*)&vreg0;
      const ushort* ce = (const ushort*)&vreg1;
#pragma unroll
      for (int jj = 0; jj < 8; ++jj) {
        VTs[cur ^ 1][(dg * 8 + jj) * VST + 2 * kp]     = ae[jj];
        VTs[cur ^ 1][(dg * 8 + jj) * VST + 2 * kp + 1] = ce[jj];
      }
    }
  }

  // ---- epilogue: row = (reg&3) + 8*(reg>>2) + 4*hi, col = q32 (same layout for L)
#pragma unroll
  for (int p = 0; p < 4; ++p) {
#pragma unroll
    for (int r = 0; r < 4; ++r) {
      int qrow = r + 8 * p + 4 * hi;
      float linv = 1.0f / lacc[4 * p + r];
      ushort* orow = attn_o + (size_t)(b * SEQ + q0 + w * 32 + qrow) * 1024 + h * 64 + q32;
      orow[0]  = f2bf(oacc0[4 * p + r] * linv);
      orow[32] = f2bf(oacc1[4 * p + r] * linv);
    }
  }
}

extern "C" void kernel_launch(void* const* d_in, const int* in_sizes, int n_in,
                              void* d_out, int out_size, void* d_ws, size_t ws_size,
                              hipStream_t stream) {
  bool ok_n  = (n_in == 3);
  bool ok_s0 = ok_n && (in_sizes[0] == 4 * 2048 * 1024);
  bool ok_s1 = ok_n && (in_sizes[1] == 1024 * 3072);
  bool ok_s2 = ok_n && (in_sizes[2] == 1024 * 1024);
  bool ok_o  = (out_size == 4 * 2048 * 1024);
  bool ok_w  = (ws_size >= (size_t)8192 * 3072 * 4);
  if (!(ok_n && ok_s0 && ok_s1 && ok_s2 && ok_o && ok_w)) {
    float c = 64.0f + 1.0f * ok_n + 2.0f * ok_s0 + 4.0f * ok_s1 +
              8.0f * ok_s2 + 16.0f * ok_o + 32.0f * ok_w;
    fill_f32<<<(out_size + 255) / 256, 256, 0, stream>>>((float*)d_out, out_size, c);
    return;
  }

  const float* x     = (const float*)d_in[0];  // [8192][1024]
  const float* w_qkv = (const float*)d_in[1];  // [1024][3072]
  const float* w_out = (const float*)d_in[2];  // [1024][1024]

  char* ws = (char*)d_ws;
  ushort* qkv    = (ushort*)ws;                                  // 48 MB
  ushort* xb     = (ushort*)(ws + (size_t)48 * 1024 * 1024);     // 16 MB
  ushort* attn_o = (ushort*)(ws + (size_t)64 * 1024 * 1024);     // 16 MB
  ushort* wqkvT  = (ushort*)(ws + (size_t)80 * 1024 * 1024);     // 6 MB
  ushort* woutT  = (ushort*)(ws + (size_t)86 * 1024 * 1024);     // 2 MB

  cast_bf16<<<dim3(8192 * 1024 / 8 / 256), dim3(256), 0, stream>>>(x, xb, 8192 * 1024 / 8);
  transpose_f32_bf16<<<dim3(3072 / 32, 1024 / 32), dim3(32, 8), 0, stream>>>(w_qkv, wqkvT, 1024, 3072);
  transpose_f32_bf16<<<dim3(1024 / 32, 1024 / 32), dim3(32, 8), 0, stream>>>(w_out, woutT, 1024, 1024);

  gemm_mfma<ushort><<<dim3(3072 / 128, 8192 / 128), dim3(256), 0, stream>>>(
      xb, wqkvT, qkv, 8192, 3072, 1024);

  attn_mfma<<<dim3(1024), dim3(256), 0, stream>>>(qkv, attn_o);

  gemm_mfma<float><<<dim3(1024 / 128, 8192 / 128), dim3(256), 0, stream>>>(
      attn_o, woutT, (float*)d_out, 8192, 1024, 1024);
}